// Round 13
// baseline (615.209 us; speedup 1.0000x reference)
//
#include <hip/hip_runtime.h>
#include <cstdio>
#include <cstdint>

#define LRELU 0.2f
#define BN_EPS 1e-5f

typedef short bf16x8 __attribute__((ext_vector_type(8)));
typedef float f32x4 __attribute__((ext_vector_type(4)));

__device__ inline unsigned short f2bf(float f) {
  unsigned int u = __float_as_uint(f);
  u += 0x7fffu + ((u >> 16) & 1u);   // RNE
  return (unsigned short)(u >> 16);
}
__device__ inline float bf2f(unsigned short v) {
  return __uint_as_float(((unsigned int)v) << 16);
}
__device__ inline float bflo(unsigned int u) { return __uint_as_float(u << 16); }
__device__ inline float bfhi(unsigned int u) { return __uint_as_float(u & 0xffff0000u); }

// =========== CSR build (bucketed: bucket = dst>>8, NB = ceil(N/256)) ========
// bpair packed to 4 B: (src<<8)|(dst&255), src < 2^24.
// Hist kernel also does weight cast AND the edge_attr passthrough copy
// (grid-stride, 2048 blocks so the 102 MB copy gets full BW — R7 lesson).

__global__ __launch_bounds__(256) void k_bhist_cast_copy(
    const int* __restrict__ dst, int* __restrict__ bh, int E,
    const float* __restrict__ W0, const float* __restrict__ W1,
    const float* __restrict__ W2,
    unsigned short* __restrict__ Wt0, unsigned short* __restrict__ Wt1,
    unsigned short* __restrict__ Wt2,
    const f32x4* __restrict__ ea, f32x4* __restrict__ oea) {
  __shared__ int cnt[512];
  const int gid = blockIdx.x * blockDim.x + threadIdx.x;
  const int gstride = gridDim.x * blockDim.x;
  // fused weight cast+transpose (24576 elems; independent of hist)
  if (gid < 24576) {
    int o = gid;
    if (o < 16384) {
      int n = o >> 7, k = o & 127;
      Wt0[o] = f2bf(W0[k * 128 + n]);
    } else if (o < 20480) {
      int p = o - 16384, n = p >> 5, k = p & 31;
      Wt1[p] = f2bf(W1[k * 128 + n]);
    } else {
      int p = o - 20480, n = p >> 5, k = p & 31;
      Wt2[p] = f2bf(W2[k * 128 + n]);
    }
  }
  for (int b = threadIdx.x; b < 512; b += 256) cnt[b] = 0;
  __syncthreads();
  for (int i = gid; i < E; i += gstride) atomicAdd(&cnt[dst[i] >> 8], 1);
  // fused edge_attr passthrough (nontemporal: no cache pollution)
  const int n4 = E * 2;
  for (int i = gid; i < n4; i += gstride) {
    f32x4 v = __builtin_nontemporal_load(&ea[i]);
    __builtin_nontemporal_store(v, &oea[i]);
  }
  __syncthreads();
  for (int b = threadIdx.x; b < 512; b += 256)
    if (cnt[b]) atomicAdd(&bh[b], cnt[b]);
}

// redundant per-block exclusive scan of bh[512] -> bsc[513] (LDS)
__device__ inline void scan_bh(const int* __restrict__ bh, int* pre, int* bsc) {
  const int t = threadIdx.x;
  const int a0 = bh[2 * t];
  const int a1 = bh[2 * t + 1];
  int s = a0 + a1;
  pre[t] = s;
  __syncthreads();
  for (int st = 1; st < 256; st <<= 1) {
    int u = (t >= st) ? pre[t - st] : 0;
    __syncthreads();
    pre[t] += u;
    __syncthreads();
  }
  const int ex = pre[t] - s;
  bsc[2 * t] = ex;
  bsc[2 * t + 1] = ex + a0;
  if (t == 255) bsc[512] = pre[255];
  __syncthreads();
}

__global__ __launch_bounds__(256) void k_bscatter(const int* __restrict__ src,
                                                  const int* __restrict__ dst,
                                                  const int* __restrict__ bh,
                                                  int* __restrict__ bclaim,
                                                  unsigned int* __restrict__ bpair,
                                                  int E) {
  __shared__ int pre[256];
  __shared__ int bsc[513];
  __shared__ int cnt[512];
  scan_bh(bh, pre, bsc);
  const int chunk = (E + gridDim.x - 1) / gridDim.x;
  const int beg = blockIdx.x * chunk;
  const int end = min(E, beg + chunk);
  for (int b = threadIdx.x; b < 512; b += 256) cnt[b] = 0;
  __syncthreads();
  for (int e = beg + threadIdx.x; e < end; e += 256)
    atomicAdd(&cnt[dst[e] >> 8], 1);
  __syncthreads();
  for (int b = threadIdx.x; b < 512; b += 256) {
    int c = cnt[b];
    cnt[b] = (c > 0) ? (bsc[b] + atomicAdd(&bclaim[b], c)) : 0;
  }
  __syncthreads();
  for (int e = beg + threadIdx.x; e < end; e += 256) {
    int d = dst[e];
    int pos = atomicAdd(&cnt[d >> 8], 1);
    bpair[pos] = ((unsigned)src[e] << 8) | ((unsigned)d & 255u);
  }
}

// per-bucket: LDS hist of 256 dsts -> LDS scan -> offs + placement
__global__ __launch_bounds__(256) void k_bcsr(const unsigned int* __restrict__ bpair,
                                              const int* __restrict__ bh,
                                              int* __restrict__ offs,
                                              int* __restrict__ srcs, int N, int E) {
  __shared__ int pre[256];
  __shared__ int bsc[513];
  __shared__ int sc[256];
  __shared__ int cur[256];
  scan_bh(bh, pre, bsc);
  const int b = blockIdx.x;
  const int lo = b << 8;
  const int t = threadIdx.x;
  const int e0 = bsc[b], e1 = bsc[b + 1];
  sc[t] = 0;
  __syncthreads();
  for (int e = e0 + t; e < e1; e += 256) atomicAdd(&sc[bpair[e] & 255u], 1);
  __syncthreads();
  int v = sc[t];
  for (int s = 1; s < 256; s <<= 1) {
    int u = (t >= s) ? sc[t - s] : 0;
    __syncthreads();
    sc[t] += u;
    __syncthreads();
  }
  const int pos0 = e0 + sc[t] - v;   // exclusive
  cur[t] = pos0;
  if (lo + t < N) offs[lo + t] = pos0;
  if (b == 0 && t == 0) offs[N] = E;
  __syncthreads();
  for (int e = e0 + t; e < e1; e += 256) {
    unsigned int p = bpair[e];
    int pos = atomicAdd(&cur[p & 255u], 1);
    srcs[pos] = (int)(p >> 8);
  }
}

// ====== MFMA GEMM + fused attention logits (+ optional fused BN+ReLU) =======
template <int K, bool BN>
__global__ __launch_bounds__(256) void k_mfma(
    const float* __restrict__ Ain, const unsigned short* __restrict__ Wt,
    const float* __restrict__ asrc, const float* __restrict__ adst,
    const float* __restrict__ stats, const float* __restrict__ g,
    const float* __restrict__ be,
    unsigned short* __restrict__ h, float* __restrict__ als,
    float* __restrict__ ald, int N) {
  __shared__ unsigned short lsh[4][16 * 132];
  __shared__ float sc_s[32], sh_s[32];
  const int wv   = threadIdx.x >> 6;
  const int lane = threadIdx.x & 63;
  const int quad = lane >> 4;
  const int col  = lane & 15;
  const int m0   = blockIdx.x * 64 + wv * 16;
  const int rowc = min(m0 + col, N - 1);

  if constexpr (BN) {
    if (threadIdx.x < 32) {
      float s = 0.f, ss = 0.f;
#pragma unroll
      for (int r = 0; r < 8; r++) {
        s  += stats[r * 64 + threadIdx.x];
        ss += stats[r * 64 + 32 + threadIdx.x];
      }
      const float inv = 1.f / (float)N;
      const float mu = s * inv;
      const float var = ss * inv - mu * mu;   // biased, as in ref
      const float scv = g[threadIdx.x] * rsqrtf(var + BN_EPS);
      sc_s[threadIdx.x] = scv;
      sh_s[threadIdx.x] = be[threadIdx.x] - mu * scv;
    }
    __syncthreads();
  }

  f32x4 acc[8];
#pragma unroll
  for (int t = 0; t < 8; t++) acc[t] = (f32x4){0.f, 0.f, 0.f, 0.f};

#pragma unroll
  for (int ks = 0; ks < K / 32; ks++) {
    const int k0 = ks * 32 + quad * 8;
    const float* ap = Ain + (size_t)rowc * K + k0;
    float4 f0 = *(const float4*)ap;
    float4 f1 = *(const float4*)(ap + 4);
    bf16x8 a;
    if constexpr (BN) {
      f0.x = fmaxf(0.f, fmaf(f0.x, sc_s[k0 + 0], sh_s[k0 + 0]));
      f0.y = fmaxf(0.f, fmaf(f0.y, sc_s[k0 + 1], sh_s[k0 + 1]));
      f0.z = fmaxf(0.f, fmaf(f0.z, sc_s[k0 + 2], sh_s[k0 + 2]));
      f0.w = fmaxf(0.f, fmaf(f0.w, sc_s[k0 + 3], sh_s[k0 + 3]));
      f1.x = fmaxf(0.f, fmaf(f1.x, sc_s[k0 + 4], sh_s[k0 + 4]));
      f1.y = fmaxf(0.f, fmaf(f1.y, sc_s[k0 + 5], sh_s[k0 + 5]));
      f1.z = fmaxf(0.f, fmaf(f1.z, sc_s[k0 + 6], sh_s[k0 + 6]));
      f1.w = fmaxf(0.f, fmaf(f1.w, sc_s[k0 + 7], sh_s[k0 + 7]));
    }
    a[0] = (short)f2bf(f0.x); a[1] = (short)f2bf(f0.y);
    a[2] = (short)f2bf(f0.z); a[3] = (short)f2bf(f0.w);
    a[4] = (short)f2bf(f1.x); a[5] = (short)f2bf(f1.y);
    a[6] = (short)f2bf(f1.z); a[7] = (short)f2bf(f1.w);
#pragma unroll
    for (int t = 0; t < 8; t++) {
      bf16x8 b = *(const bf16x8*)(Wt + (size_t)(t * 16 + col) * K + k0);
      acc[t] = __builtin_amdgcn_mfma_f32_16x16x32_bf16(a, b, acc[t], 0, 0, 0);
    }
  }

#pragma unroll
  for (int t = 0; t < 8; t++) {
#pragma unroll
    for (int j = 0; j < 4; j++)
      lsh[wv][(quad * 4 + j) * 132 + col + 16 * t] = f2bf(acc[t][j]);
  }
  __syncthreads();

  float as8[8], ad8[8];
#pragma unroll
  for (int j = 0; j < 8; j++) {
    as8[j] = asrc[col * 8 + j];
    ad8[j] = adst[col * 8 + j];
  }

#pragma unroll
  for (int i = 0; i < 4; i++) {
    const int row = i * 4 + quad;
    const int hrow = m0 + row;
    const unsigned short* rp = &lsh[wv][row * 132 + col * 8];
    ushort4 lo = *(const ushort4*)rp;
    ushort4 hi = *(const ushort4*)(rp + 4);
    float p = 0.f, q = 0.f, v;
    v = bf2f(lo.x); p += v * as8[0]; q += v * ad8[0];
    v = bf2f(lo.y); p += v * as8[1]; q += v * ad8[1];
    v = bf2f(lo.z); p += v * as8[2]; q += v * ad8[2];
    v = bf2f(lo.w); p += v * as8[3]; q += v * ad8[3];
    v = bf2f(hi.x); p += v * as8[4]; q += v * ad8[4];
    v = bf2f(hi.y); p += v * as8[5]; q += v * ad8[5];
    v = bf2f(hi.z); p += v * as8[6]; q += v * ad8[6];
    v = bf2f(hi.w); p += v * as8[7]; q += v * ad8[7];
    if (hrow < N) {
      ushort4* gp = (ushort4*)(h + (size_t)hrow * 128 + col * 8);
      gp[0] = lo; gp[1] = hi;
    }
    p += __shfl_xor(p, 1); p += __shfl_xor(p, 2);
    q += __shfl_xor(q, 1); q += __shfl_xor(q, 2);
    if ((lane & 3) == 0 && hrow < N) {
      const int head = col >> 2;
      als[hrow * 4 + head] = p;
      ald[hrow * 4 + head] = q;
    }
  }
}

// ====== per-dst aggregation: 2 edges/wave, software-pipelined gathers =======
// FROZEN hot loop (verified R3/R10/R12): traffic-bound at ~2.6 TB/s for
// 224 MB of L2-miss traffic. Split into TWO node-range dispatches per layer
// (node0 param) so each instance is ~47 us -> top-5 table can reveal any
// hidden >47 us kernel next round (diagnostic by construction).
template <bool STATS>
__global__ __launch_bounds__(256) void k_agg(
    const unsigned int* __restrict__ h2, const float* __restrict__ als,
    const float* __restrict__ ald, const int* __restrict__ offs,
    const int* __restrict__ srcs, const float* __restrict__ bias,
    float* __restrict__ y, float* __restrict__ stats, int node0, int nend) {
  __shared__ float s1[32], s2[32];
  const int node = node0 + blockIdx.x * 4 + (threadIdx.x >> 6);
  const int lane = threadIdx.x & 63;
  const bool valid = node < nend;
  if constexpr (STATS) {
    if (threadIdx.x < 32) { s1[threadIdx.x] = 0.f; s2[threadIdx.x] = 0.f; }
    __syncthreads();
  } else {
    if (!valid) return;
  }

  if (valid) {
    const int half = lane >> 5;        // which edge of a pair
    const int sub  = lane & 31;        // owns channels 4*sub..4*sub+3
    const int head = sub >> 3;
    const int beg = __builtin_amdgcn_readfirstlane(offs[node]);
    const int end = __builtin_amdgcn_readfirstlane(offs[node + 1]);
    const float ad = ald[node * 4 + head];
    float ax0 = 0.f, ax1 = 0.f, ax2 = 0.f, ax3 = 0.f, dn = 0.f;

    for (int base = beg; base < end; base += 64) {
      const int mm = min(64, end - base);
      const int sv = srcs[base + min(lane, mm - 1)];
      const int vlim = mm - half;      // slot i valid iff i < vlim (per-lane)

      float aA0, aA1, aA2, aA3, aB0, aB1, aB2, aB3;
      uint2 uA0, uA1, uA2, uA3, uB0, uB1, uB2, uB3;
      int iA0, iA1, iA2, iA3, iB0, iB1, iB2, iB3;

#define SLOT(S, K, I)                                                      \
  {                                                                        \
    i##S##K = (I);                                                         \
    const int c0 = min((I), mm - 1), c1 = min((I) + 1, mm - 1);            \
    const int sA_ = __builtin_amdgcn_readlane(sv, c0);                     \
    const int sB_ = __builtin_amdgcn_readlane(sv, c1);                     \
    const int s_ = half ? sB_ : sA_;                                       \
    a##S##K = als[s_ * 4 + head];                                          \
    u##S##K = *(const uint2*)(h2 + (size_t)s_ * 64 + (sub << 1));          \
  }
#define ISSUE(S, J0) SLOT(S, 0, (J0)) SLOT(S, 1, (J0) + 2)                 \
                     SLOT(S, 2, (J0) + 4) SLOT(S, 3, (J0) + 6)
#define CSLOT(S, K)                                                        \
  {                                                                        \
    float e_ = a##S##K + ad;                                               \
    e_ = fmaxf(e_, LRELU * e_);                                            \
    float w_ = __expf(e_);                                                 \
    w_ = (i##S##K < vlim) ? w_ : 0.f;                                      \
    dn += w_;                                                              \
    ax0 = fmaf(w_, bflo(u##S##K.x), ax0);                                  \
    ax1 = fmaf(w_, bfhi(u##S##K.x), ax1);                                  \
    ax2 = fmaf(w_, bflo(u##S##K.y), ax2);                                  \
    ax3 = fmaf(w_, bfhi(u##S##K.y), ax3);                                  \
  }
#define COMPUTE(S) CSLOT(S, 0) CSLOT(S, 1) CSLOT(S, 2) CSLOT(S, 3)

      int j0 = 0;
      ISSUE(A, 0)
      j0 = 8;
      if (j0 >= mm) {
        COMPUTE(A)
      } else {
        for (;;) {
          ISSUE(B, j0) COMPUTE(A)
          j0 += 8;
          if (j0 >= mm) { COMPUTE(B) break; }
          ISSUE(A, j0) COMPUTE(B)
          j0 += 8;
          if (j0 >= mm) { COMPUTE(A) break; }
        }
      }
#undef SLOT
#undef ISSUE
#undef CSLOT
#undef COMPUTE
    }

    // per-head denominator: sum the two halves (lane^32 has same head)
    dn += __shfl_xor(dn, 32);
    const float r = (dn > 0.f) ? (1.f / dn) : 0.f;
    ax0 *= r; ax1 *= r; ax2 *= r; ax3 *= r;
    // sum halves, then heads (head bits are lane bits 3,4)
    ax0 += __shfl_xor(ax0, 32); ax1 += __shfl_xor(ax1, 32);
    ax2 += __shfl_xor(ax2, 32); ax3 += __shfl_xor(ax3, 32);
    ax0 += __shfl_xor(ax0, 8);  ax1 += __shfl_xor(ax1, 8);
    ax2 += __shfl_xor(ax2, 8);  ax3 += __shfl_xor(ax3, 8);
    ax0 += __shfl_xor(ax0, 16); ax1 += __shfl_xor(ax1, 16);
    ax2 += __shfl_xor(ax2, 16); ax3 += __shfl_xor(ax3, 16);

    if (lane < 8) {
      float4 b4 = ((const float4*)bias)[lane];
      float4 o;
      o.x = 0.25f * ax0 + b4.x;
      o.y = 0.25f * ax1 + b4.y;
      o.z = 0.25f * ax2 + b4.z;
      o.w = 0.25f * ax3 + b4.w;
      ((float4*)(y + (size_t)node * 32))[lane] = o;
      if constexpr (STATS) {
        atomicAdd(&s1[4 * lane + 0], o.x); atomicAdd(&s2[4 * lane + 0], o.x * o.x);
        atomicAdd(&s1[4 * lane + 1], o.y); atomicAdd(&s2[4 * lane + 1], o.y * o.y);
        atomicAdd(&s1[4 * lane + 2], o.z); atomicAdd(&s2[4 * lane + 2], o.z * o.z);
        atomicAdd(&s1[4 * lane + 3], o.w); atomicAdd(&s2[4 * lane + 3], o.w * o.w);
      }
    }
  }

  if constexpr (STATS) {
    __syncthreads();
    if (threadIdx.x < 32) {
      float* sb = stats + (blockIdx.x & 7) * 64;
      atomicAdd(&sb[threadIdx.x], s1[threadIdx.x]);
      atomicAdd(&sb[32 + threadIdx.x], s2[threadIdx.x]);
    }
  }
}

// ---------------- launch ----------------
extern "C" void kernel_launch(void* const* d_in, const int* in_sizes, int n_in,
                              void* d_out, int out_size, void* d_ws, size_t ws_size,
                              hipStream_t stream) {
  const float* x   = (const float*)d_in[0];
  const int*   ei  = (const int*)d_in[1];
  const float* ea  = (const float*)d_in[2];
  const float* W0  = (const float*)d_in[3];
  const float* as0 = (const float*)d_in[4];
  const float* ad0 = (const float*)d_in[5];
  const float* b0  = (const float*)d_in[6];
  const float* g0  = (const float*)d_in[7];
  const float* be0 = (const float*)d_in[8];
  const float* W1  = (const float*)d_in[9];
  const float* as1 = (const float*)d_in[10];
  const float* ad1 = (const float*)d_in[11];
  const float* b1  = (const float*)d_in[12];
  const float* g1  = (const float*)d_in[13];
  const float* be1 = (const float*)d_in[14];
  const float* W2  = (const float*)d_in[15];
  const float* as2 = (const float*)d_in[16];
  const float* ad2 = (const float*)d_in[17];
  const float* b2  = (const float*)d_in[18];

  const int N = in_sizes[0] / 128;
  const int E = in_sizes[1] / 2;
  const int* srcI = ei;
  const int* dstI = ei + E;
  const int NB = (N + 255) >> 8;

  char* w = (char*)d_ws;
  auto carve = [&](size_t bytes) -> void* {
    void* p = (void*)w;
    w += (bytes + 255) & ~(size_t)255;
    return p;
  };
  unsigned short* h  = (unsigned short*)carve((size_t)N * 128 * 2);
  float* als        = (float*)carve((size_t)N * 4 * 4);
  float* ald        = (float*)carve((size_t)N * 4 * 4);
  float* y          = (float*)carve((size_t)N * 32 * 4);
  int* offs         = (int*)carve((size_t)(N + 1) * 4);
  int* srcs         = (int*)carve((size_t)E * 4);
  // zero-init region: bh + bclaim + stats covered by ONE small memset (8 KB)
  int* bh           = (int*)carve(512 * 4);
  int* bclaim       = (int*)carve(512 * 4);
  float* stats      = (float*)carve(1024 * 4);   // 2 layers x 8 replicas x 64
  char* zend        = w;
  unsigned short* Wt0 = (unsigned short*)carve(128 * 128 * 2);
  unsigned short* Wt1 = (unsigned short*)carve(128 * 32 * 2);
  unsigned short* Wt2 = (unsigned short*)carve(128 * 32 * 2);
  if ((size_t)(w - (char*)d_ws) > ws_size) {
    fprintf(stderr, "GAT kernel: ws too small (%zu needed, %zu given)\n",
            (size_t)(w - (char*)d_ws), ws_size);
    return;
  }
  unsigned int* bpair = (unsigned int*)h;   // aliases h; consumed before h write

  float* out_nodes = (float*)d_out;
  float* out_ea    = out_nodes + (size_t)N * 32;

  (void)hipMemsetAsync(bh, 0, (size_t)(zend - (char*)bh), stream);

  k_bhist_cast_copy<<<2048, 256, 0, stream>>>(dstI, bh, E, W0, W1, W2,
                                              Wt0, Wt1, Wt2,
                                              (const f32x4*)ea, (f32x4*)out_ea);
  k_bscatter<<<512, 256, 0, stream>>>(srcI, dstI, bh, bclaim, bpair, E);
  k_bcsr<<<NB, 256, 0, stream>>>(bpair, bh, offs, srcs, N, E);

  const int gGemm = (N + 63) / 64;
  // split each agg into two ~equal node-range dispatches (multiple of 4)
  const int halfN = ((N / 2) + 3) & ~3;
  const int gA0 = (halfN + 3) / 4;
  const int gA1 = (N - halfN + 3) / 4;

  // layer 0
  k_mfma<128, false><<<gGemm, 256, 0, stream>>>(x, Wt0, as0, ad0,
                                                nullptr, nullptr, nullptr,
                                                h, als, ald, N);
  k_agg<true><<<gA0, 256, 0, stream>>>((const unsigned int*)h, als, ald, offs,
                                       srcs, b0, y, stats, 0, halfN);
  k_agg<true><<<gA1, 256, 0, stream>>>((const unsigned int*)h, als, ald, offs,
                                       srcs, b0, y, stats, halfN, N);
  // layer 1 (BN-final + BN+ReLU fused into GEMM A-load)
  k_mfma<32, true><<<gGemm, 256, 0, stream>>>(y, Wt1, as1, ad1, stats, g0, be0,
                                              h, als, ald, N);
  k_agg<true><<<gA0, 256, 0, stream>>>((const unsigned int*)h, als, ald, offs,
                                       srcs, b1, y, stats + 512, 0, halfN);
  k_agg<true><<<gA1, 256, 0, stream>>>((const unsigned int*)h, als, ald, offs,
                                       srcs, b1, y, stats + 512, halfN, N);
  // layer 2 (writes node output directly to d_out)
  k_mfma<32, true><<<gGemm, 256, 0, stream>>>(y, Wt2, as2, ad2, stats + 512, g1, be1,
                                              h, als, ald, N);
  k_agg<false><<<gA0, 256, 0, stream>>>((const unsigned int*)h, als, ald, offs,
                                        srcs, b2, out_nodes, nullptr, 0, halfN);
  k_agg<false><<<gA1, 256, 0, stream>>>((const unsigned int*)h, als, ald, offs,
                                        srcs, b2, out_nodes, nullptr, halfN, N);
}

// Round 14
// 580.858 us; speedup vs baseline: 1.0591x; 1.0591x over previous
//
#include <hip/hip_runtime.h>
#include <cstdio>
#include <cstdint>

#define LRELU 0.2f
#define BN_EPS 1e-5f

typedef short bf16x8 __attribute__((ext_vector_type(8)));
typedef float f32x4 __attribute__((ext_vector_type(4)));

__device__ inline unsigned short f2bf(float f) {
  unsigned int u = __float_as_uint(f);
  u += 0x7fffu + ((u >> 16) & 1u);   // RNE
  return (unsigned short)(u >> 16);
}
__device__ inline float bf2f(unsigned short v) {
  return __uint_as_float(((unsigned int)v) << 16);
}
__device__ inline float bflo(unsigned int u) { return __uint_as_float(u << 16); }
__device__ inline float bfhi(unsigned int u) { return __uint_as_float(u & 0xffff0000u); }

// =========== CSR build (bucketed: bucket = dst>>8, NB = ceil(N/256)) ========
// bpair packed to 4 B: (src<<8)|(dst&255), src < 2^24.

__global__ __launch_bounds__(256) void k_bhist_cast_copy(
    const int* __restrict__ dst, int* __restrict__ bh, int E,
    const float* __restrict__ W0, const float* __restrict__ W1,
    const float* __restrict__ W2,
    unsigned short* __restrict__ Wt0, unsigned short* __restrict__ Wt1,
    unsigned short* __restrict__ Wt2,
    const f32x4* __restrict__ ea, f32x4* __restrict__ oea) {
  __shared__ int cnt[512];
  const int gid = blockIdx.x * blockDim.x + threadIdx.x;
  const int gstride = gridDim.x * blockDim.x;
  if (gid < 24576) {
    int o = gid;
    if (o < 16384) {
      int n = o >> 7, k = o & 127;
      Wt0[o] = f2bf(W0[k * 128 + n]);
    } else if (o < 20480) {
      int p = o - 16384, n = p >> 5, k = p & 31;
      Wt1[p] = f2bf(W1[k * 128 + n]);
    } else {
      int p = o - 20480, n = p >> 5, k = p & 31;
      Wt2[p] = f2bf(W2[k * 128 + n]);
    }
  }
  for (int b = threadIdx.x; b < 512; b += 256) cnt[b] = 0;
  __syncthreads();
  for (int i = gid; i < E; i += gstride) atomicAdd(&cnt[dst[i] >> 8], 1);
  const int n4 = E * 2;
  for (int i = gid; i < n4; i += gstride) {
    f32x4 v = __builtin_nontemporal_load(&ea[i]);
    __builtin_nontemporal_store(v, &oea[i]);
  }
  __syncthreads();
  for (int b = threadIdx.x; b < 512; b += 256)
    if (cnt[b]) atomicAdd(&bh[b], cnt[b]);
}

// redundant per-block exclusive scan of bh[512] -> bsc[513] (LDS)
__device__ inline void scan_bh(const int* __restrict__ bh, int* pre, int* bsc) {
  const int t = threadIdx.x;
  const int a0 = bh[2 * t];
  const int a1 = bh[2 * t + 1];
  int s = a0 + a1;
  pre[t] = s;
  __syncthreads();
  for (int st = 1; st < 256; st <<= 1) {
    int u = (t >= st) ? pre[t - st] : 0;
    __syncthreads();
    pre[t] += u;
    __syncthreads();
  }
  const int ex = pre[t] - s;
  bsc[2 * t] = ex;
  bsc[2 * t + 1] = ex + a0;
  if (t == 255) bsc[512] = pre[255];
  __syncthreads();
}

__global__ __launch_bounds__(256) void k_bscatter(const int* __restrict__ src,
                                                  const int* __restrict__ dst,
                                                  const int* __restrict__ bh,
                                                  int* __restrict__ bclaim,
                                                  unsigned int* __restrict__ bpair,
                                                  int E) {
  __shared__ int pre[256];
  __shared__ int bsc[513];
  __shared__ int cnt[512];
  scan_bh(bh, pre, bsc);
  const int chunk = (E + gridDim.x - 1) / gridDim.x;
  const int beg = blockIdx.x * chunk;
  const int end = min(E, beg + chunk);
  for (int b = threadIdx.x; b < 512; b += 256) cnt[b] = 0;
  __syncthreads();
  for (int e = beg + threadIdx.x; e < end; e += 256)
    atomicAdd(&cnt[dst[e] >> 8], 1);
  __syncthreads();
  for (int b = threadIdx.x; b < 512; b += 256) {
    int c = cnt[b];
    cnt[b] = (c > 0) ? (bsc[b] + atomicAdd(&bclaim[b], c)) : 0;
  }
  __syncthreads();
  for (int e = beg + threadIdx.x; e < end; e += 256) {
    int d = dst[e];
    int pos = atomicAdd(&cnt[d >> 8], 1);
    bpair[pos] = ((unsigned)src[e] << 8) | ((unsigned)d & 255u);
  }
}

// per-bucket: LDS hist of 256 dsts -> LDS scan -> offs + placement
__global__ __launch_bounds__(256) void k_bcsr(const unsigned int* __restrict__ bpair,
                                              const int* __restrict__ bh,
                                              int* __restrict__ offs,
                                              int* __restrict__ srcs, int N, int E) {
  __shared__ int pre[256];
  __shared__ int bsc[513];
  __shared__ int sc[256];
  __shared__ int cur[256];
  scan_bh(bh, pre, bsc);
  const int b = blockIdx.x;
  const int lo = b << 8;
  const int t = threadIdx.x;
  const int e0 = bsc[b], e1 = bsc[b + 1];
  sc[t] = 0;
  __syncthreads();
  for (int e = e0 + t; e < e1; e += 256) atomicAdd(&sc[bpair[e] & 255u], 1);
  __syncthreads();
  int v = sc[t];
  for (int s = 1; s < 256; s <<= 1) {
    int u = (t >= s) ? sc[t - s] : 0;
    __syncthreads();
    sc[t] += u;
    __syncthreads();
  }
  const int pos0 = e0 + sc[t] - v;   // exclusive
  cur[t] = pos0;
  if (lo + t < N) offs[lo + t] = pos0;
  if (b == 0 && t == 0) offs[N] = E;
  __syncthreads();
  for (int e = e0 + t; e < e1; e += 256) {
    unsigned int p = bpair[e];
    int pos = atomicAdd(&cur[p & 255u], 1);
    srcs[pos] = (int)(p >> 8);
  }
}

// ====== MFMA GEMM + fused attention logits (+ optional fused BN+ReLU) =======
// R13 diagnosis: old 64-row version was latency-bound (MfmaUtil 2%, VALU 7%,
// BW 0.92 TB/s, all idle) — too few load-bytes in flight + block barrier
// coupling 4 waves to slowest scattered load. Fix: (a) 2 row-tiles per block
// (2x MLP, B-fragments shared), (b) no LDS barrier — lsh[wv] is wave-private
// (same-wave DS ops are in-order), so only the BN preamble barrier remains.
template <int K, bool BN>
__global__ __launch_bounds__(256) void k_mfma(
    const float* __restrict__ Ain, const unsigned short* __restrict__ Wt,
    const float* __restrict__ asrc, const float* __restrict__ adst,
    const float* __restrict__ stats, const float* __restrict__ g,
    const float* __restrict__ be,
    unsigned short* __restrict__ h, float* __restrict__ als,
    float* __restrict__ ald, int N) {
  __shared__ unsigned short lsh[4][16 * 132];
  __shared__ float sc_s[32], sh_s[32];
  const int wv   = threadIdx.x >> 6;
  const int lane = threadIdx.x & 63;
  const int quad = lane >> 4;
  const int col  = lane & 15;
  const int m0   = blockIdx.x * 128 + wv * 16;   // tile0 rows
  const int m1   = m0 + 64;                      // tile1 rows
  const int rowc0 = min(m0 + col, N - 1);
  const int rowc1 = min(m1 + col, N - 1);

  if constexpr (BN) {
    if (threadIdx.x < 32) {
      float s = 0.f, ss = 0.f;
#pragma unroll
      for (int r = 0; r < 8; r++) {
        s  += stats[r * 64 + threadIdx.x];
        ss += stats[r * 64 + 32 + threadIdx.x];
      }
      const float inv = 1.f / (float)N;
      const float mu = s * inv;
      const float var = ss * inv - mu * mu;   // biased, as in ref
      const float scv = g[threadIdx.x] * rsqrtf(var + BN_EPS);
      sc_s[threadIdx.x] = scv;
      sh_s[threadIdx.x] = be[threadIdx.x] - mu * scv;
    }
    __syncthreads();
  }

  f32x4 acc0[8], acc1[8];
#pragma unroll
  for (int t = 0; t < 8; t++) {
    acc0[t] = (f32x4){0.f, 0.f, 0.f, 0.f};
    acc1[t] = (f32x4){0.f, 0.f, 0.f, 0.f};
  }

#pragma unroll
  for (int ks = 0; ks < K / 32; ks++) {
    const int k0 = ks * 32 + quad * 8;
    const float* ap0 = Ain + (size_t)rowc0 * K + k0;
    const float* ap1 = Ain + (size_t)rowc1 * K + k0;
    float4 f0 = *(const float4*)ap0;
    float4 f1 = *(const float4*)(ap0 + 4);
    float4 e0 = *(const float4*)ap1;
    float4 e1 = *(const float4*)(ap1 + 4);
    if constexpr (BN) {
      const float s0 = sc_s[k0 + 0], h0 = sh_s[k0 + 0];
      const float s1 = sc_s[k0 + 1], h1 = sh_s[k0 + 1];
      const float s2 = sc_s[k0 + 2], h2 = sh_s[k0 + 2];
      const float s3 = sc_s[k0 + 3], h3 = sh_s[k0 + 3];
      const float s4 = sc_s[k0 + 4], h4 = sh_s[k0 + 4];
      const float s5 = sc_s[k0 + 5], h5 = sh_s[k0 + 5];
      const float s6 = sc_s[k0 + 6], h6 = sh_s[k0 + 6];
      const float s7 = sc_s[k0 + 7], h7 = sh_s[k0 + 7];
      f0.x = fmaxf(0.f, fmaf(f0.x, s0, h0)); e0.x = fmaxf(0.f, fmaf(e0.x, s0, h0));
      f0.y = fmaxf(0.f, fmaf(f0.y, s1, h1)); e0.y = fmaxf(0.f, fmaf(e0.y, s1, h1));
      f0.z = fmaxf(0.f, fmaf(f0.z, s2, h2)); e0.z = fmaxf(0.f, fmaf(e0.z, s2, h2));
      f0.w = fmaxf(0.f, fmaf(f0.w, s3, h3)); e0.w = fmaxf(0.f, fmaf(e0.w, s3, h3));
      f1.x = fmaxf(0.f, fmaf(f1.x, s4, h4)); e1.x = fmaxf(0.f, fmaf(e1.x, s4, h4));
      f1.y = fmaxf(0.f, fmaf(f1.y, s5, h5)); e1.y = fmaxf(0.f, fmaf(e1.y, s5, h5));
      f1.z = fmaxf(0.f, fmaf(f1.z, s6, h6)); e1.z = fmaxf(0.f, fmaf(e1.z, s6, h6));
      f1.w = fmaxf(0.f, fmaf(f1.w, s7, h7)); e1.w = fmaxf(0.f, fmaf(e1.w, s7, h7));
    }
    bf16x8 a0, a1;
    a0[0] = (short)f2bf(f0.x); a0[1] = (short)f2bf(f0.y);
    a0[2] = (short)f2bf(f0.z); a0[3] = (short)f2bf(f0.w);
    a0[4] = (short)f2bf(f1.x); a0[5] = (short)f2bf(f1.y);
    a0[6] = (short)f2bf(f1.z); a0[7] = (short)f2bf(f1.w);
    a1[0] = (short)f2bf(e0.x); a1[1] = (short)f2bf(e0.y);
    a1[2] = (short)f2bf(e0.z); a1[3] = (short)f2bf(e0.w);
    a1[4] = (short)f2bf(e1.x); a1[5] = (short)f2bf(e1.y);
    a1[6] = (short)f2bf(e1.z); a1[7] = (short)f2bf(e1.w);
#pragma unroll
    for (int t = 0; t < 8; t++) {
      bf16x8 b = *(const bf16x8*)(Wt + (size_t)(t * 16 + col) * K + k0);
      acc0[t] = __builtin_amdgcn_mfma_f32_16x16x32_bf16(a0, b, acc0[t], 0, 0, 0);
      acc1[t] = __builtin_amdgcn_mfma_f32_16x16x32_bf16(a1, b, acc1[t], 0, 0, 0);
    }
  }

  float as8[8], ad8[8];
#pragma unroll
  for (int j = 0; j < 8; j++) {
    as8[j] = asrc[col * 8 + j];
    ad8[j] = adst[col * 8 + j];
  }

  // epilogue per tile: lsh[wv] is wave-private; DS ops in-order -> no barrier
#define EPILOGUE(MM, ACC)                                                    \
  {                                                                          \
    _Pragma("unroll") for (int t = 0; t < 8; t++) {                          \
      _Pragma("unroll") for (int j = 0; j < 4; j++)                          \
          lsh[wv][(quad * 4 + j) * 132 + col + 16 * t] = f2bf(ACC[t][j]);    \
    }                                                                        \
    _Pragma("unroll") for (int i = 0; i < 4; i++) {                          \
      const int row = i * 4 + quad;                                          \
      const int hrow = (MM) + row;                                           \
      const unsigned short* rp = &lsh[wv][row * 132 + col * 8];              \
      ushort4 lo = *(const ushort4*)rp;                                      \
      ushort4 hi = *(const ushort4*)(rp + 4);                                \
      float p = 0.f, q = 0.f, v;                                             \
      v = bf2f(lo.x); p += v * as8[0]; q += v * ad8[0];                      \
      v = bf2f(lo.y); p += v * as8[1]; q += v * ad8[1];                      \
      v = bf2f(lo.z); p += v * as8[2]; q += v * ad8[2];                      \
      v = bf2f(lo.w); p += v * as8[3]; q += v * ad8[3];                      \
      v = bf2f(hi.x); p += v * as8[4]; q += v * ad8[4];                      \
      v = bf2f(hi.y); p += v * as8[5]; q += v * ad8[5];                      \
      v = bf2f(hi.z); p += v * as8[6]; q += v * ad8[6];                      \
      v = bf2f(hi.w); p += v * as8[7]; q += v * ad8[7];                      \
      if (hrow < N) {                                                        \
        ushort4* gp = (ushort4*)(h + (size_t)hrow * 128 + col * 8);          \
        gp[0] = lo; gp[1] = hi;                                              \
      }                                                                      \
      p += __shfl_xor(p, 1); p += __shfl_xor(p, 2);                          \
      q += __shfl_xor(q, 1); q += __shfl_xor(q, 2);                          \
      if ((lane & 3) == 0 && hrow < N) {                                     \
        const int head = col >> 2;                                           \
        als[hrow * 4 + head] = p;                                            \
        ald[hrow * 4 + head] = q;                                            \
      }                                                                      \
    }                                                                        \
  }

  EPILOGUE(m0, acc0)
  EPILOGUE(m1, acc1)
#undef EPILOGUE
}

// ====== per-dst aggregation: 2 edges/wave, software-pipelined gathers =======
// FROZEN hot loop (verified R3/R10/R12): traffic-bound at ~2.6 TB/s for
// 224 MB of L2-miss traffic. Single launch per layer (R13: splitting cost
// +38 us — diagnostic only, reverted).
template <bool STATS>
__global__ __launch_bounds__(256) void k_agg(
    const unsigned int* __restrict__ h2, const float* __restrict__ als,
    const float* __restrict__ ald, const int* __restrict__ offs,
    const int* __restrict__ srcs, const float* __restrict__ bias,
    float* __restrict__ y, float* __restrict__ stats, int N) {
  __shared__ float s1[32], s2[32];
  const int node = blockIdx.x * 4 + (threadIdx.x >> 6);
  const int lane = threadIdx.x & 63;
  const bool valid = node < N;
  if constexpr (STATS) {
    if (threadIdx.x < 32) { s1[threadIdx.x] = 0.f; s2[threadIdx.x] = 0.f; }
    __syncthreads();
  } else {
    if (!valid) return;
  }

  if (valid) {
    const int half = lane >> 5;        // which edge of a pair
    const int sub  = lane & 31;        // owns channels 4*sub..4*sub+3
    const int head = sub >> 3;
    const int beg = __builtin_amdgcn_readfirstlane(offs[node]);
    const int end = __builtin_amdgcn_readfirstlane(offs[node + 1]);
    const float ad = ald[node * 4 + head];
    float ax0 = 0.f, ax1 = 0.f, ax2 = 0.f, ax3 = 0.f, dn = 0.f;

    for (int base = beg; base < end; base += 64) {
      const int mm = min(64, end - base);
      const int sv = srcs[base + min(lane, mm - 1)];
      const int vlim = mm - half;      // slot i valid iff i < vlim (per-lane)

      float aA0, aA1, aA2, aA3, aB0, aB1, aB2, aB3;
      uint2 uA0, uA1, uA2, uA3, uB0, uB1, uB2, uB3;
      int iA0, iA1, iA2, iA3, iB0, iB1, iB2, iB3;

#define SLOT(S, K, I)                                                      \
  {                                                                        \
    i##S##K = (I);                                                         \
    const int c0 = min((I), mm - 1), c1 = min((I) + 1, mm - 1);            \
    const int sA_ = __builtin_amdgcn_readlane(sv, c0);                     \
    const int sB_ = __builtin_amdgcn_readlane(sv, c1);                     \
    const int s_ = half ? sB_ : sA_;                                       \
    a##S##K = als[s_ * 4 + head];                                          \
    u##S##K = *(const uint2*)(h2 + (size_t)s_ * 64 + (sub << 1));          \
  }
#define ISSUE(S, J0) SLOT(S, 0, (J0)) SLOT(S, 1, (J0) + 2)                 \
                     SLOT(S, 2, (J0) + 4) SLOT(S, 3, (J0) + 6)
#define CSLOT(S, K)                                                        \
  {                                                                        \
    float e_ = a##S##K + ad;                                               \
    e_ = fmaxf(e_, LRELU * e_);                                            \
    float w_ = __expf(e_);                                                 \
    w_ = (i##S##K < vlim) ? w_ : 0.f;                                      \
    dn += w_;                                                              \
    ax0 = fmaf(w_, bflo(u##S##K.x), ax0);                                  \
    ax1 = fmaf(w_, bfhi(u##S##K.x), ax1);                                  \
    ax2 = fmaf(w_, bflo(u##S##K.y), ax2);                                  \
    ax3 = fmaf(w_, bfhi(u##S##K.y), ax3);                                  \
  }
#define COMPUTE(S) CSLOT(S, 0) CSLOT(S, 1) CSLOT(S, 2) CSLOT(S, 3)

      int j0 = 0;
      ISSUE(A, 0)
      j0 = 8;
      if (j0 >= mm) {
        COMPUTE(A)
      } else {
        for (;;) {
          ISSUE(B, j0) COMPUTE(A)
          j0 += 8;
          if (j0 >= mm) { COMPUTE(B) break; }
          ISSUE(A, j0) COMPUTE(B)
          j0 += 8;
          if (j0 >= mm) { COMPUTE(A) break; }
        }
      }
#undef SLOT
#undef ISSUE
#undef CSLOT
#undef COMPUTE
    }

    // per-head denominator: sum the two halves (lane^32 has same head)
    dn += __shfl_xor(dn, 32);
    const float r = (dn > 0.f) ? (1.f / dn) : 0.f;
    ax0 *= r; ax1 *= r; ax2 *= r; ax3 *= r;
    // sum halves, then heads (head bits are lane bits 3,4)
    ax0 += __shfl_xor(ax0, 32); ax1 += __shfl_xor(ax1, 32);
    ax2 += __shfl_xor(ax2, 32); ax3 += __shfl_xor(ax3, 32);
    ax0 += __shfl_xor(ax0, 8);  ax1 += __shfl_xor(ax1, 8);
    ax2 += __shfl_xor(ax2, 8);  ax3 += __shfl_xor(ax3, 8);
    ax0 += __shfl_xor(ax0, 16); ax1 += __shfl_xor(ax1, 16);
    ax2 += __shfl_xor(ax2, 16); ax3 += __shfl_xor(ax3, 16);

    if (lane < 8) {
      float4 b4 = ((const float4*)bias)[lane];
      float4 o;
      o.x = 0.25f * ax0 + b4.x;
      o.y = 0.25f * ax1 + b4.y;
      o.z = 0.25f * ax2 + b4.z;
      o.w = 0.25f * ax3 + b4.w;
      ((float4*)(y + (size_t)node * 32))[lane] = o;
      if constexpr (STATS) {
        atomicAdd(&s1[4 * lane + 0], o.x); atomicAdd(&s2[4 * lane + 0], o.x * o.x);
        atomicAdd(&s1[4 * lane + 1], o.y); atomicAdd(&s2[4 * lane + 1], o.y * o.y);
        atomicAdd(&s1[4 * lane + 2], o.z); atomicAdd(&s2[4 * lane + 2], o.z * o.z);
        atomicAdd(&s1[4 * lane + 3], o.w); atomicAdd(&s2[4 * lane + 3], o.w * o.w);
      }
    }
  }

  if constexpr (STATS) {
    __syncthreads();
    if (threadIdx.x < 32) {
      float* sb = stats + (blockIdx.x & 7) * 64;
      atomicAdd(&sb[threadIdx.x], s1[threadIdx.x]);
      atomicAdd(&sb[32 + threadIdx.x], s2[threadIdx.x]);
    }
  }
}

// ---------------- launch ----------------
extern "C" void kernel_launch(void* const* d_in, const int* in_sizes, int n_in,
                              void* d_out, int out_size, void* d_ws, size_t ws_size,
                              hipStream_t stream) {
  const float* x   = (const float*)d_in[0];
  const int*   ei  = (const int*)d_in[1];
  const float* ea  = (const float*)d_in[2];
  const float* W0  = (const float*)d_in[3];
  const float* as0 = (const float*)d_in[4];
  const float* ad0 = (const float*)d_in[5];
  const float* b0  = (const float*)d_in[6];
  const float* g0  = (const float*)d_in[7];
  const float* be0 = (const float*)d_in[8];
  const float* W1  = (const float*)d_in[9];
  const float* as1 = (const float*)d_in[10];
  const float* ad1 = (const float*)d_in[11];
  const float* b1  = (const float*)d_in[12];
  const float* g1  = (const float*)d_in[13];
  const float* be1 = (const float*)d_in[14];
  const float* W2  = (const float*)d_in[15];
  const float* as2 = (const float*)d_in[16];
  const float* ad2 = (const float*)d_in[17];
  const float* b2  = (const float*)d_in[18];

  const int N = in_sizes[0] / 128;
  const int E = in_sizes[1] / 2;
  const int* srcI = ei;
  const int* dstI = ei + E;
  const int NB = (N + 255) >> 8;

  char* w = (char*)d_ws;
  auto carve = [&](size_t bytes) -> void* {
    void* p = (void*)w;
    w += (bytes + 255) & ~(size_t)255;
    return p;
  };
  unsigned short* h  = (unsigned short*)carve((size_t)N * 128 * 2);
  float* als        = (float*)carve((size_t)N * 4 * 4);
  float* ald        = (float*)carve((size_t)N * 4 * 4);
  float* y          = (float*)carve((size_t)N * 32 * 4);
  int* offs         = (int*)carve((size_t)(N + 1) * 4);
  int* srcs         = (int*)carve((size_t)E * 4);
  // zero-init region: bh + bclaim + stats covered by ONE small memset (8 KB)
  int* bh           = (int*)carve(512 * 4);
  int* bclaim       = (int*)carve(512 * 4);
  float* stats      = (float*)carve(1024 * 4);   // 2 layers x 8 replicas x 64
  char* zend        = w;
  unsigned short* Wt0 = (unsigned short*)carve(128 * 128 * 2);
  unsigned short* Wt1 = (unsigned short*)carve(128 * 32 * 2);
  unsigned short* Wt2 = (unsigned short*)carve(128 * 32 * 2);
  if ((size_t)(w - (char*)d_ws) > ws_size) {
    fprintf(stderr, "GAT kernel: ws too small (%zu needed, %zu given)\n",
            (size_t)(w - (char*)d_ws), ws_size);
    return;
  }
  unsigned int* bpair = (unsigned int*)h;   // aliases h; consumed before h write

  float* out_nodes = (float*)d_out;
  float* out_ea    = out_nodes + (size_t)N * 32;

  (void)hipMemsetAsync(bh, 0, (size_t)(zend - (char*)bh), stream);

  k_bhist_cast_copy<<<2048, 256, 0, stream>>>(dstI, bh, E, W0, W1, W2,
                                              Wt0, Wt1, Wt2,
                                              (const f32x4*)ea, (f32x4*)out_ea);
  k_bscatter<<<512, 256, 0, stream>>>(srcI, dstI, bh, bclaim, bpair, E);
  k_bcsr<<<NB, 256, 0, stream>>>(bpair, bh, offs, srcs, N, E);

  const int gGemm = (N + 127) / 128;   // 2 row-tiles per block
  const int gAgg  = (N + 3) / 4;

  // layer 0
  k_mfma<128, false><<<gGemm, 256, 0, stream>>>(x, Wt0, as0, ad0,
                                                nullptr, nullptr, nullptr,
                                                h, als, ald, N);
  k_agg<true><<<gAgg, 256, 0, stream>>>((const unsigned int*)h, als, ald, offs,
                                        srcs, b0, y, stats, N);
  // layer 1 (BN-final + BN+ReLU fused into GEMM A-load)
  k_mfma<32, true><<<gGemm, 256, 0, stream>>>(y, Wt1, as1, ad1, stats, g0, be0,
                                              h, als, ald, N);
  k_agg<true><<<gAgg, 256, 0, stream>>>((const unsigned int*)h, als, ald, offs,
                                        srcs, b1, y, stats + 512, N);
  // layer 2 (writes node output directly to d_out)
  k_mfma<32, true><<<gGemm, 256, 0, stream>>>(y, Wt2, as2, ad2, stats + 512, g1, be1,
                                              h, als, ald, N);
  k_agg<false><<<gAgg, 256, 0, stream>>>((const unsigned int*)h, als, ald, offs,
                                         srcs, b2, out_nodes, nullptr, N);
}

// Round 15
// 544.300 us; speedup vs baseline: 1.1303x; 1.0672x over previous
//
#include <hip/hip_runtime.h>
#include <cstdio>
#include <cstdint>

#define LRELU 0.2f
#define BN_EPS 1e-5f

typedef short bf16x8 __attribute__((ext_vector_type(8)));
typedef float f32x4 __attribute__((ext_vector_type(4)));

__device__ inline unsigned short f2bf(float f) {
  unsigned int u = __float_as_uint(f);
  u += 0x7fffu + ((u >> 16) & 1u);   // RNE
  return (unsigned short)(u >> 16);
}
__device__ inline float bf2f(unsigned short v) {
  return __uint_as_float(((unsigned int)v) << 16);
}
__device__ inline float bflo(unsigned int u) { return __uint_as_float(u << 16); }
__device__ inline float bfhi(unsigned int u) { return __uint_as_float(u & 0xffff0000u); }

// =========== CSR build (bucketed: bucket = dst>>8, NB = ceil(N/256)) ========
// bpair packed to 4 B: (src<<8)|(dst&255), src < 2^24. bpair NO LONGER
// aliases h (scatter now runs concurrently with mfma L0 which writes h).

__global__ __launch_bounds__(256) void k_bhist_cast(
    const int* __restrict__ dst, int* __restrict__ bh, int E,
    const float* __restrict__ W0, const float* __restrict__ W1,
    const float* __restrict__ W2,
    unsigned short* __restrict__ Wt0, unsigned short* __restrict__ Wt1,
    unsigned short* __restrict__ Wt2) {
  __shared__ int cnt[512];
  const int gid = blockIdx.x * blockDim.x + threadIdx.x;
  const int gstride = gridDim.x * blockDim.x;
  if (gid < 24576) {
    int o = gid;
    if (o < 16384) {
      int n = o >> 7, k = o & 127;
      Wt0[o] = f2bf(W0[k * 128 + n]);
    } else if (o < 20480) {
      int p = o - 16384, n = p >> 5, k = p & 31;
      Wt1[p] = f2bf(W1[k * 128 + n]);
    } else {
      int p = o - 20480, n = p >> 5, k = p & 31;
      Wt2[p] = f2bf(W2[k * 128 + n]);
    }
  }
  for (int b = threadIdx.x; b < 512; b += 256) cnt[b] = 0;
  __syncthreads();
  for (int i = gid; i < E; i += gstride) atomicAdd(&cnt[dst[i] >> 8], 1);
  __syncthreads();
  for (int b = threadIdx.x; b < 512; b += 256)
    if (cnt[b]) atomicAdd(&bh[b], cnt[b]);
}

// redundant per-block exclusive scan of bh[512] -> bsc[513] (LDS)
__device__ __forceinline__ void scan_bh(const int* __restrict__ bh, int* pre,
                                        int* bsc) {
  const int t = threadIdx.x;
  const int a0 = bh[2 * t];
  const int a1 = bh[2 * t + 1];
  int s = a0 + a1;
  pre[t] = s;
  __syncthreads();
  for (int st = 1; st < 256; st <<= 1) {
    int u = (t >= st) ? pre[t - st] : 0;
    __syncthreads();
    pre[t] += u;
    __syncthreads();
  }
  const int ex = pre[t] - s;
  bsc[2 * t] = ex;
  bsc[2 * t + 1] = ex + a0;
  if (t == 255) bsc[512] = pre[255];
  __syncthreads();
}

__device__ __forceinline__ void bscatter_body(
    int bid, int SCB, int* pre, int* bsc, int* cnt,
    const int* __restrict__ src, const int* __restrict__ dst,
    const int* __restrict__ bh, int* __restrict__ bclaim,
    unsigned int* __restrict__ bpair, int E) {
  scan_bh(bh, pre, bsc);
  const int chunk = (E + SCB - 1) / SCB;
  const int beg = bid * chunk;
  const int end = min(E, beg + chunk);
  for (int b = threadIdx.x; b < 512; b += 256) cnt[b] = 0;
  __syncthreads();
  for (int e = beg + threadIdx.x; e < end; e += 256)
    atomicAdd(&cnt[dst[e] >> 8], 1);
  __syncthreads();
  for (int b = threadIdx.x; b < 512; b += 256) {
    int c = cnt[b];
    cnt[b] = (c > 0) ? (bsc[b] + atomicAdd(&bclaim[b], c)) : 0;
  }
  __syncthreads();
  for (int e = beg + threadIdx.x; e < end; e += 256) {
    int d = dst[e];
    int pos = atomicAdd(&cnt[d >> 8], 1);
    bpair[pos] = ((unsigned)src[e] << 8) | ((unsigned)d & 255u);
  }
}

// per-bucket: LDS hist of 256 dsts -> LDS scan -> offs + placement
__global__ __launch_bounds__(256) void k_bcsr(const unsigned int* __restrict__ bpair,
                                              const int* __restrict__ bh,
                                              int* __restrict__ offs,
                                              int* __restrict__ srcs, int N, int E) {
  __shared__ int pre[256];
  __shared__ int bsc[513];
  __shared__ int sc[256];
  __shared__ int cur[256];
  scan_bh(bh, pre, bsc);
  const int b = blockIdx.x;
  const int lo = b << 8;
  const int t = threadIdx.x;
  const int e0 = bsc[b], e1 = bsc[b + 1];
  sc[t] = 0;
  __syncthreads();
  for (int e = e0 + t; e < e1; e += 256) atomicAdd(&sc[bpair[e] & 255u], 1);
  __syncthreads();
  int v = sc[t];
  for (int s = 1; s < 256; s <<= 1) {
    int u = (t >= s) ? sc[t - s] : 0;
    __syncthreads();
    sc[t] += u;
    __syncthreads();
  }
  const int pos0 = e0 + sc[t] - v;   // exclusive
  cur[t] = pos0;
  if (lo + t < N) offs[lo + t] = pos0;
  if (b == 0 && t == 0) offs[N] = E;
  __syncthreads();
  for (int e = e0 + t; e < e1; e += 256) {
    unsigned int p = bpair[e];
    int pos = atomicAdd(&cur[p & 255u], 1);
    srcs[pos] = (int)(p >> 8);
  }
}

// ====== MFMA GEMM + fused attention logits (+ optional fused BN+ReLU) =======
// 128 rows/block (2 tiles/wave), no epilogue barrier (lsh[wv] wave-private).
template <int K, bool BN>
__device__ __forceinline__ void mfma_body(
    int bid, unsigned short (*lsh)[2112], float* sc_s, float* sh_s,
    const float* __restrict__ Ain, const unsigned short* __restrict__ Wt,
    const float* __restrict__ asrc, const float* __restrict__ adst,
    const float* __restrict__ stats, const float* __restrict__ g,
    const float* __restrict__ be,
    unsigned short* __restrict__ h, float* __restrict__ als,
    float* __restrict__ ald, int N) {
  const int wv   = threadIdx.x >> 6;
  const int lane = threadIdx.x & 63;
  const int quad = lane >> 4;
  const int col  = lane & 15;
  const int m0   = bid * 128 + wv * 16;
  const int m1   = m0 + 64;
  const int rowc0 = min(m0 + col, N - 1);
  const int rowc1 = min(m1 + col, N - 1);

  if constexpr (BN) {
    if (threadIdx.x < 32) {
      float s = 0.f, ss = 0.f;
#pragma unroll
      for (int r = 0; r < 8; r++) {
        s  += stats[r * 64 + threadIdx.x];
        ss += stats[r * 64 + 32 + threadIdx.x];
      }
      const float inv = 1.f / (float)N;
      const float mu = s * inv;
      const float var = ss * inv - mu * mu;   // biased, as in ref
      const float scv = g[threadIdx.x] * rsqrtf(var + BN_EPS);
      sc_s[threadIdx.x] = scv;
      sh_s[threadIdx.x] = be[threadIdx.x] - mu * scv;
    }
    __syncthreads();
  }

  f32x4 acc0[8], acc1[8];
#pragma unroll
  for (int t = 0; t < 8; t++) {
    acc0[t] = (f32x4){0.f, 0.f, 0.f, 0.f};
    acc1[t] = (f32x4){0.f, 0.f, 0.f, 0.f};
  }

#pragma unroll
  for (int ks = 0; ks < K / 32; ks++) {
    const int k0 = ks * 32 + quad * 8;
    const float* ap0 = Ain + (size_t)rowc0 * K + k0;
    const float* ap1 = Ain + (size_t)rowc1 * K + k0;
    float4 f0 = *(const float4*)ap0;
    float4 f1 = *(const float4*)(ap0 + 4);
    float4 e0 = *(const float4*)ap1;
    float4 e1 = *(const float4*)(ap1 + 4);
    if constexpr (BN) {
      const float s0 = sc_s[k0 + 0], h0 = sh_s[k0 + 0];
      const float s1 = sc_s[k0 + 1], h1 = sh_s[k0 + 1];
      const float s2 = sc_s[k0 + 2], h2 = sh_s[k0 + 2];
      const float s3 = sc_s[k0 + 3], h3 = sh_s[k0 + 3];
      const float s4 = sc_s[k0 + 4], h4 = sh_s[k0 + 4];
      const float s5 = sc_s[k0 + 5], h5 = sh_s[k0 + 5];
      const float s6 = sc_s[k0 + 6], h6 = sh_s[k0 + 6];
      const float s7 = sc_s[k0 + 7], h7 = sh_s[k0 + 7];
      f0.x = fmaxf(0.f, fmaf(f0.x, s0, h0)); e0.x = fmaxf(0.f, fmaf(e0.x, s0, h0));
      f0.y = fmaxf(0.f, fmaf(f0.y, s1, h1)); e0.y = fmaxf(0.f, fmaf(e0.y, s1, h1));
      f0.z = fmaxf(0.f, fmaf(f0.z, s2, h2)); e0.z = fmaxf(0.f, fmaf(e0.z, s2, h2));
      f0.w = fmaxf(0.f, fmaf(f0.w, s3, h3)); e0.w = fmaxf(0.f, fmaf(e0.w, s3, h3));
      f1.x = fmaxf(0.f, fmaf(f1.x, s4, h4)); e1.x = fmaxf(0.f, fmaf(e1.x, s4, h4));
      f1.y = fmaxf(0.f, fmaf(f1.y, s5, h5)); e1.y = fmaxf(0.f, fmaf(e1.y, s5, h5));
      f1.z = fmaxf(0.f, fmaf(f1.z, s6, h6)); e1.z = fmaxf(0.f, fmaf(e1.z, s6, h6));
      f1.w = fmaxf(0.f, fmaf(f1.w, s7, h7)); e1.w = fmaxf(0.f, fmaf(e1.w, s7, h7));
    }
    bf16x8 a0, a1;
    a0[0] = (short)f2bf(f0.x); a0[1] = (short)f2bf(f0.y);
    a0[2] = (short)f2bf(f0.z); a0[3] = (short)f2bf(f0.w);
    a0[4] = (short)f2bf(f1.x); a0[5] = (short)f2bf(f1.y);
    a0[6] = (short)f2bf(f1.z); a0[7] = (short)f2bf(f1.w);
    a1[0] = (short)f2bf(e0.x); a1[1] = (short)f2bf(e0.y);
    a1[2] = (short)f2bf(e0.z); a1[3] = (short)f2bf(e0.w);
    a1[4] = (short)f2bf(e1.x); a1[5] = (short)f2bf(e1.y);
    a1[6] = (short)f2bf(e1.z); a1[7] = (short)f2bf(e1.w);
#pragma unroll
    for (int t = 0; t < 8; t++) {
      bf16x8 b = *(const bf16x8*)(Wt + (size_t)(t * 16 + col) * K + k0);
      acc0[t] = __builtin_amdgcn_mfma_f32_16x16x32_bf16(a0, b, acc0[t], 0, 0, 0);
      acc1[t] = __builtin_amdgcn_mfma_f32_16x16x32_bf16(a1, b, acc1[t], 0, 0, 0);
    }
  }

  float as8[8], ad8[8];
#pragma unroll
  for (int j = 0; j < 8; j++) {
    as8[j] = asrc[col * 8 + j];
    ad8[j] = adst[col * 8 + j];
  }

#define EPILOGUE(MM, ACC)                                                    \
  {                                                                          \
    _Pragma("unroll") for (int t = 0; t < 8; t++) {                          \
      _Pragma("unroll") for (int j = 0; j < 4; j++)                          \
          lsh[wv][(quad * 4 + j) * 132 + col + 16 * t] = f2bf(ACC[t][j]);    \
    }                                                                        \
    _Pragma("unroll") for (int i = 0; i < 4; i++) {                          \
      const int row = i * 4 + quad;                                          \
      const int hrow = (MM) + row;                                           \
      const unsigned short* rp = &lsh[wv][row * 132 + col * 8];              \
      ushort4 lo = *(const ushort4*)rp;                                      \
      ushort4 hi = *(const ushort4*)(rp + 4);                                \
      float p = 0.f, q = 0.f, v;                                             \
      v = bf2f(lo.x); p += v * as8[0]; q += v * ad8[0];                      \
      v = bf2f(lo.y); p += v * as8[1]; q += v * ad8[1];                      \
      v = bf2f(lo.z); p += v * as8[2]; q += v * ad8[2];                      \
      v = bf2f(lo.w); p += v * as8[3]; q += v * ad8[3];                      \
      v = bf2f(hi.x); p += v * as8[4]; q += v * ad8[4];                      \
      v = bf2f(hi.y); p += v * as8[5]; q += v * ad8[5];                      \
      v = bf2f(hi.z); p += v * as8[6]; q += v * ad8[6];                      \
      v = bf2f(hi.w); p += v * as8[7]; q += v * ad8[7];                      \
      if (hrow < N) {                                                        \
        ushort4* gp = (ushort4*)(h + (size_t)hrow * 128 + col * 8);          \
        gp[0] = lo; gp[1] = hi;                                              \
      }                                                                      \
      p += __shfl_xor(p, 1); p += __shfl_xor(p, 2);                          \
      q += __shfl_xor(q, 1); q += __shfl_xor(q, 2);                          \
      if ((lane & 3) == 0 && hrow < N) {                                     \
        const int head = col >> 2;                                           \
        als[hrow * 4 + head] = p;                                            \
        ald[hrow * 4 + head] = q;                                            \
      }                                                                      \
    }                                                                        \
  }

  EPILOGUE(m0, acc0)
  EPILOGUE(m1, acc1)
#undef EPILOGUE
}

template <int K, bool BN>
__global__ __launch_bounds__(256) void k_mfma(
    const float* __restrict__ Ain, const unsigned short* __restrict__ Wt,
    const float* __restrict__ asrc, const float* __restrict__ adst,
    const float* __restrict__ stats, const float* __restrict__ g,
    const float* __restrict__ be,
    unsigned short* __restrict__ h, float* __restrict__ als,
    float* __restrict__ ald, int N) {
  __shared__ unsigned short lsh[4][2112];
  __shared__ float sc_s[32], sh_s[32];
  mfma_body<K, BN>(blockIdx.x, lsh, sc_s, sh_s, Ain, Wt, asrc, adst,
                   stats, g, be, h, als, ald, N);
}

// ====== fused: bucket-scatter (blocks [0,SCB)) || mfma L0 (rest) ===========
// Independent work co-scheduled: scatter is atomic-bound (~25 us), mfma L0
// latency-bound (~59 us, <35% util) — block-role split overlaps them since
// multi-stream/events are unavailable under graph capture.
__global__ __launch_bounds__(256) void k_sc_mfma(
    const int* __restrict__ src, const int* __restrict__ dst,
    const int* __restrict__ bh, int* __restrict__ bclaim,
    unsigned int* __restrict__ bpair, int E, int SCB,
    const float* __restrict__ Ain, const unsigned short* __restrict__ Wt,
    const float* __restrict__ asrc, const float* __restrict__ adst,
    unsigned short* __restrict__ h, float* __restrict__ als,
    float* __restrict__ ald, int N) {
  __shared__ __align__(16) char smraw[16896];
  if ((int)blockIdx.x < SCB) {
    int* pre = (int*)smraw;
    int* bsc = pre + 256;
    int* cnt = bsc + 513;
    bscatter_body(blockIdx.x, SCB, pre, bsc, cnt, src, dst, bh, bclaim,
                  bpair, E);
  } else {
    unsigned short (*lsh)[2112] = (unsigned short(*)[2112])smraw;
    mfma_body<128, false>(blockIdx.x - SCB, lsh, nullptr, nullptr, Ain, Wt,
                          asrc, adst, nullptr, nullptr, nullptr, h, als, ald, N);
  }
}

// ====== per-dst aggregation: 2 edges/wave, software-pipelined gathers =======
// FROZEN hot loop (verified R3/R10/R12). COPY variant: blocks >= aggBlocks
// do the edge_attr passthrough (nontemporal), hidden under agg's
// fabric-latency-bound time (agg uses only ~2.6 of 6.3 TB/s).
template <bool STATS, bool COPY>
__global__ __launch_bounds__(256) void k_agg(
    const unsigned int* __restrict__ h2, const float* __restrict__ als,
    const float* __restrict__ ald, const int* __restrict__ offs,
    const int* __restrict__ srcs, const float* __restrict__ bias,
    float* __restrict__ y, float* __restrict__ stats, int N,
    int aggBlocks, const f32x4* __restrict__ cs, f32x4* __restrict__ cd,
    int cn) {
  if constexpr (COPY) {
    if ((int)blockIdx.x >= aggBlocks) {
      const int cb = blockIdx.x - aggBlocks;
      for (int i = cb * 256 + threadIdx.x; i < cn; i += 1024 * 256) {
        f32x4 v = __builtin_nontemporal_load(&cs[i]);
        __builtin_nontemporal_store(v, &cd[i]);
      }
      return;
    }
  }
  __shared__ float s1[32], s2[32];
  const int node = blockIdx.x * 4 + (threadIdx.x >> 6);
  const int lane = threadIdx.x & 63;
  const bool valid = node < N;
  if constexpr (STATS) {
    if (threadIdx.x < 32) { s1[threadIdx.x] = 0.f; s2[threadIdx.x] = 0.f; }
    __syncthreads();
  } else {
    if (!valid) return;
  }

  if (valid) {
    const int half = lane >> 5;        // which edge of a pair
    const int sub  = lane & 31;        // owns channels 4*sub..4*sub+3
    const int head = sub >> 3;
    const int beg = __builtin_amdgcn_readfirstlane(offs[node]);
    const int end = __builtin_amdgcn_readfirstlane(offs[node + 1]);
    const float ad = ald[node * 4 + head];
    float ax0 = 0.f, ax1 = 0.f, ax2 = 0.f, ax3 = 0.f, dn = 0.f;

    for (int base = beg; base < end; base += 64) {
      const int mm = min(64, end - base);
      const int sv = srcs[base + min(lane, mm - 1)];
      const int vlim = mm - half;      // slot i valid iff i < vlim (per-lane)

      float aA0, aA1, aA2, aA3, aB0, aB1, aB2, aB3;
      uint2 uA0, uA1, uA2, uA3, uB0, uB1, uB2, uB3;
      int iA0, iA1, iA2, iA3, iB0, iB1, iB2, iB3;

#define SLOT(S, K, I)                                                      \
  {                                                                        \
    i##S##K = (I);                                                         \
    const int c0 = min((I), mm - 1), c1 = min((I) + 1, mm - 1);            \
    const int sA_ = __builtin_amdgcn_readlane(sv, c0);                     \
    const int sB_ = __builtin_amdgcn_readlane(sv, c1);                     \
    const int s_ = half ? sB_ : sA_;                                       \
    a##S##K = als[s_ * 4 + head];                                          \
    u##S##K = *(const uint2*)(h2 + (size_t)s_ * 64 + (sub << 1));          \
  }
#define ISSUE(S, J0) SLOT(S, 0, (J0)) SLOT(S, 1, (J0) + 2)                 \
                     SLOT(S, 2, (J0) + 4) SLOT(S, 3, (J0) + 6)
#define CSLOT(S, K)                                                        \
  {                                                                        \
    float e_ = a##S##K + ad;                                               \
    e_ = fmaxf(e_, LRELU * e_);                                            \
    float w_ = __expf(e_);                                                 \
    w_ = (i##S##K < vlim) ? w_ : 0.f;                                      \
    dn += w_;                                                              \
    ax0 = fmaf(w_, bflo(u##S##K.x), ax0);                                  \
    ax1 = fmaf(w_, bfhi(u##S##K.x), ax1);                                  \
    ax2 = fmaf(w_, bflo(u##S##K.y), ax2);                                  \
    ax3 = fmaf(w_, bfhi(u##S##K.y), ax3);                                  \
  }
#define COMPUTE(S) CSLOT(S, 0) CSLOT(S, 1) CSLOT(S, 2) CSLOT(S, 3)

      int j0 = 0;
      ISSUE(A, 0)
      j0 = 8;
      if (j0 >= mm) {
        COMPUTE(A)
      } else {
        for (;;) {
          ISSUE(B, j0) COMPUTE(A)
          j0 += 8;
          if (j0 >= mm) { COMPUTE(B) break; }
          ISSUE(A, j0) COMPUTE(B)
          j0 += 8;
          if (j0 >= mm) { COMPUTE(A) break; }
        }
      }
#undef SLOT
#undef ISSUE
#undef CSLOT
#undef COMPUTE
    }

    // per-head denominator: sum the two halves (lane^32 has same head)
    dn += __shfl_xor(dn, 32);
    const float r = (dn > 0.f) ? (1.f / dn) : 0.f;
    ax0 *= r; ax1 *= r; ax2 *= r; ax3 *= r;
    // sum halves, then heads (head bits are lane bits 3,4)
    ax0 += __shfl_xor(ax0, 32); ax1 += __shfl_xor(ax1, 32);
    ax2 += __shfl_xor(ax2, 32); ax3 += __shfl_xor(ax3, 32);
    ax0 += __shfl_xor(ax0, 8);  ax1 += __shfl_xor(ax1, 8);
    ax2 += __shfl_xor(ax2, 8);  ax3 += __shfl_xor(ax3, 8);
    ax0 += __shfl_xor(ax0, 16); ax1 += __shfl_xor(ax1, 16);
    ax2 += __shfl_xor(ax2, 16); ax3 += __shfl_xor(ax3, 16);

    if (lane < 8) {
      float4 b4 = ((const float4*)bias)[lane];
      float4 o;
      o.x = 0.25f * ax0 + b4.x;
      o.y = 0.25f * ax1 + b4.y;
      o.z = 0.25f * ax2 + b4.z;
      o.w = 0.25f * ax3 + b4.w;
      ((float4*)(y + (size_t)node * 32))[lane] = o;
      if constexpr (STATS) {
        atomicAdd(&s1[4 * lane + 0], o.x); atomicAdd(&s2[4 * lane + 0], o.x * o.x);
        atomicAdd(&s1[4 * lane + 1], o.y); atomicAdd(&s2[4 * lane + 1], o.y * o.y);
        atomicAdd(&s1[4 * lane + 2], o.z); atomicAdd(&s2[4 * lane + 2], o.z * o.z);
        atomicAdd(&s1[4 * lane + 3], o.w); atomicAdd(&s2[4 * lane + 3], o.w * o.w);
      }
    }
  }

  if constexpr (STATS) {
    __syncthreads();
    if (threadIdx.x < 32) {
      float* sb = stats + (blockIdx.x & 7) * 64;
      atomicAdd(&sb[threadIdx.x], s1[threadIdx.x]);
      atomicAdd(&sb[32 + threadIdx.x], s2[threadIdx.x]);
    }
  }
}

// ---------------- launch ----------------
extern "C" void kernel_launch(void* const* d_in, const int* in_sizes, int n_in,
                              void* d_out, int out_size, void* d_ws, size_t ws_size,
                              hipStream_t stream) {
  const float* x   = (const float*)d_in[0];
  const int*   ei  = (const int*)d_in[1];
  const float* ea  = (const float*)d_in[2];
  const float* W0  = (const float*)d_in[3];
  const float* as0 = (const float*)d_in[4];
  const float* ad0 = (const float*)d_in[5];
  const float* b0  = (const float*)d_in[6];
  const float* g0  = (const float*)d_in[7];
  const float* be0 = (const float*)d_in[8];
  const float* W1  = (const float*)d_in[9];
  const float* as1 = (const float*)d_in[10];
  const float* ad1 = (const float*)d_in[11];
  const float* b1  = (const float*)d_in[12];
  const float* g1  = (const float*)d_in[13];
  const float* be1 = (const float*)d_in[14];
  const float* W2  = (const float*)d_in[15];
  const float* as2 = (const float*)d_in[16];
  const float* ad2 = (const float*)d_in[17];
  const float* b2  = (const float*)d_in[18];

  const int N = in_sizes[0] / 128;
  const int E = in_sizes[1] / 2;
  const int* srcI = ei;
  const int* dstI = ei + E;
  const int NB = (N + 255) >> 8;

  char* w = (char*)d_ws;
  auto carve = [&](size_t bytes) -> void* {
    void* p = (void*)w;
    w += (bytes + 255) & ~(size_t)255;
    return p;
  };
  unsigned short* h  = (unsigned short*)carve((size_t)N * 128 * 2);
  float* als        = (float*)carve((size_t)N * 4 * 4);
  float* ald        = (float*)carve((size_t)N * 4 * 4);
  float* y          = (float*)carve((size_t)N * 32 * 4);
  int* offs         = (int*)carve((size_t)(N + 1) * 4);
  int* srcs         = (int*)carve((size_t)E * 4);
  unsigned int* bpair = (unsigned int*)carve((size_t)E * 4);  // no longer aliases h
  // zero-init region: bh + bclaim + stats covered by ONE small memset (8 KB)
  int* bh           = (int*)carve(512 * 4);
  int* bclaim       = (int*)carve(512 * 4);
  float* stats      = (float*)carve(1024 * 4);   // 2 layers x 8 replicas x 64
  char* zend        = w;
  unsigned short* Wt0 = (unsigned short*)carve(128 * 128 * 2);
  unsigned short* Wt1 = (unsigned short*)carve(128 * 32 * 2);
  unsigned short* Wt2 = (unsigned short*)carve(128 * 32 * 2);
  if ((size_t)(w - (char*)d_ws) > ws_size) {
    fprintf(stderr, "GAT kernel: ws too small (%zu needed, %zu given)\n",
            (size_t)(w - (char*)d_ws), ws_size);
    return;
  }

  float* out_nodes = (float*)d_out;
  float* out_ea    = out_nodes + (size_t)N * 32;

  (void)hipMemsetAsync(bh, 0, (size_t)(zend - (char*)bh), stream);

  k_bhist_cast<<<512, 256, 0, stream>>>(dstI, bh, E, W0, W1, W2, Wt0, Wt1, Wt2);

  const int gGemm = (N + 127) / 128;   // 2 row-tiles per block
  const int gAgg  = (N + 3) / 4;
  const int SCB   = 512;
  const int n4    = E * 2;

  // bucket-scatter || mfma L0 (independent; block-role split)
  k_sc_mfma<<<SCB + gGemm, 256, 0, stream>>>(srcI, dstI, bh, bclaim, bpair, E,
                                             SCB, x, Wt0, as0, ad0,
                                             h, als, ald, N);
  k_bcsr<<<NB, 256, 0, stream>>>(bpair, bh, offs, srcs, N, E);

  // layer 0
  k_agg<true, false><<<gAgg, 256, 0, stream>>>(
      (const unsigned int*)h, als, ald, offs, srcs, b0, y, stats, N,
      0, nullptr, nullptr, 0);
  // layer 1 (BN-final + BN+ReLU fused into GEMM A-load)
  k_mfma<32, true><<<gGemm, 256, 0, stream>>>(y, Wt1, as1, ad1, stats, g0, be0,
                                              h, als, ald, N);
  k_agg<true, false><<<gAgg, 256, 0, stream>>>(
      (const unsigned int*)h, als, ald, offs, srcs, b1, y, stats + 512, N,
      0, nullptr, nullptr, 0);
  // layer 2 (writes node output directly to d_out; edge_attr copy rides along)
  k_mfma<32, true><<<gGemm, 256, 0, stream>>>(y, Wt2, as2, ad2, stats + 512, g1, be1,
                                              h, als, ald, N);
  k_agg<false, true><<<gAgg + 1024, 256, 0, stream>>>(
      (const unsigned int*)h, als, ald, offs, srcs, b2, out_nodes, nullptr, N,
      gAgg, (const f32x4*)ea, (f32x4*)out_ea, n4);
}